// Round 5
// baseline (809.364 us; speedup 1.0000x reference)
//
#include <hip/hip_runtime.h>

#define N_NODES 200000
#define N_EDGES 6400000
#define HID 200
#define NREP 8                    // x-gather replicas (one per XCD)
#define APITCH 208                // act row pitch (fp16) = 416 B, 16B-aligned
#define NSTRIP (N_NODES / 32)     // 6250 strips of 32 rows, exact
#define ACT_ELEMS (N_NODES * APITCH + 64)   // +64 pad for k-overflow reads

// Scatter partitioning (NO global atomics): 10 partitions x 20K nodes.
// Each block owns (partition p, edge-chunk c); LDS-accumulates, flushes to a
// private g_part slice; reduce_kernel sums slices. 500 blocks co-resident.
#define NPART 10
#define PNODES 20000              // 80 KB LDS -> 2 blocks/CU
#define PBLK 50                   // edge-chunks
#define CHUNK_E (N_EDGES / PBLK)  // 128000 edges, exact
#define APPLY_LDS (PNODES * 4)

// Packed B layout (R2-verified): g_wph[l][tile 13][ks 7][lane 64][j 8] =
//   W^T[n = tile*16 + (lane&15)][k = ks*32 + (lane>>4)*8 + j], zero-padded.
#define TILE_ELEMS (7 * 512)
#define PL_ELEMS (13 * TILE_ELEMS)        // 46592 elems = 93184 B per layer
#define WCHUNKS (PL_ELEMS * 2 / 16)       // 5824 16-B staging chunks
#define LDS_BIAS (PL_ELEMS * 2)
#define LDSH_TOTAL (LDS_BIAS + 208 * 4)   // 94016 B -> 1 block/CU

typedef float f32x4 __attribute__((ext_vector_type(4)));
typedef _Float16 f16x8 __attribute__((ext_vector_type(8)));
typedef unsigned short u16;
typedef unsigned int u32;

__device__ __align__(16) float g_agg[N_NODES];           // final aggregation
__device__ __align__(16) float g_xf8[NREP * N_NODES];    // fp32 x, per-XCD replica
__device__ __align__(16) float g_wf[6 * HID * HID];      // fp32 (VALU fallback)
__device__ __align__(16) _Float16 g_wph[6 * PL_ELEMS];   // fp16 packed W^T
__device__ __align__(16) float g_ev[N_EDGES];            // gathered x[src]
__device__ __align__(16) float g_part[NPART * PBLK * PNODES];  // 40 MB slices
__device__ __align__(16) _Float16 g_actA[ACT_ELEMS];
__device__ __align__(16) _Float16 g_actB[ACT_ELEMS];
__device__ int g_ctr[8];                                 // per-layer strip counters
__device__ int g_isbf;

__device__ __forceinline__ float bf2f(u16 u) {
  union { u32 i; float f; } v; v.i = ((u32)u) << 16; return v.f;
}
__device__ __forceinline__ u16 f2bf(float f) {  // RNE
  u32 i = __float_as_uint(f);
  return (u16)((i + 0x7FFFu + ((i >> 16) & 1u)) >> 16);
}
__device__ __forceinline__ float ldf(const void* p, int i, int isbf) {
  return isbf ? bf2f(((const u16*)p)[i]) : ((const float*)p)[i];
}
__device__ __forceinline__ void load_lds16(const void* g, void* l) {
  __builtin_amdgcn_global_load_lds(
      (const __attribute__((address_space(1))) u32*)g,
      (__attribute__((address_space(3))) u32*)l, 16, 0, 0);
}

// ---- rank-2 MFMA layout self-test (fp16), reference folded at compile time ----
constexpr int tf1(int m) { return (m & 3) + 1; }
constexpr int tf2(int m) { return ((m >> 2) & 3) + 2; }
constexpr int tg1(int k) { return (k & 7) + 1; }
constexpr int tg2(int k) { return ((k >> 3) & 3) + 1; }
constexpr int tu1(int k) { return ((k * 3) & 7) + 1; }
constexpr int tu2(int k) { return ((k >> 2) & 3) + 2; }
constexpr int tw1(int n) { return ((n * 5) & 7) + 1; }
constexpr int tw2(int n) { return ((n >> 2) & 3) + 1; }
constexpr int calcS(int i, int j) {
  int s = 0;
  for (int k = 0; k < 32; ++k)
    s += (i ? tg2(k) : tg1(k)) * (j ? tu2(k) : tu1(k));
  return s;
}
__device__ __forceinline__ float refD(int m, int n) {
  constexpr int S11 = calcS(0, 0), S12 = calcS(0, 1), S21 = calcS(1, 0), S22 = calcS(1, 1);
  return (float)(tf1(m) * tw1(n) * S11 + tf1(m) * tw2(n) * S12 +
                 tf2(m) * tw1(n) * S21 + tf2(m) * tw2(n) * S22);
}
__device__ int mfma_selftest(int l15, int q) {
  f16x8 av, bv;
#pragma unroll
  for (int j = 0; j < 8; ++j) {
    int k = q * 8 + j;
    av[j] = (_Float16)(float)(tf1(l15) * tg1(k) + tf2(l15) * tg2(k));
    bv[j] = (_Float16)(float)(tu1(k) * tw1(l15) + tu2(k) * tw2(l15));
  }
  f32x4 d = __builtin_amdgcn_mfma_f32_16x16x32_f16(av, bv, (f32x4){0.f, 0.f, 0.f, 0.f}, 0, 0, 0);
  bool ok0 = true, ok1 = true;
#pragma unroll
  for (int r = 0; r < 4; ++r) {
    ok0 = ok0 && (d[r] == refD(q * 4 + r, l15));
    ok1 = ok1 && (d[r] == refD(l15, q * 4 + r));
  }
  return __all(ok0) ? 0 : (__all(ok1) ? 1 : 2);
}

// ---- K0: dtype sniff ----
__global__ void sniff_kernel(const u32* __restrict__ xw) {
  int i = threadIdx.x;  // 64 threads
  u32 e = (xw[i] >> 7) & 0xFFu;
  unsigned long long b = __ballot(e >= 110u && e <= 135u);
  if (i == 0) g_isbf = (__popcll(b) >= 48) ? 1 : 0;
}

// ---- K1: replicate x + both weight forms + counters + act pads ----
__global__ void prep_kernel(const void* __restrict__ x, const void* __restrict__ w_hid) {
  int t = blockIdx.x * blockDim.x + threadIdx.x;   // 1.6M threads
  int isbf = g_isbf;
  if (t < NREP * N_NODES) {
    int qd = t / N_NODES;
    int node = t - qd * N_NODES;
    g_xf8[t] = ldf(x, node, isbf);
  }
  if (t < 6 * HID * HID) g_wf[t] = ldf(w_hid, t, isbf);
  if (t < 6 * PL_ELEMS) {
    int l = t / PL_ELEMS;
    int r = t - l * PL_ELEMS;
    int tile = r / TILE_ELEMS;
    int r2 = r - tile * TILE_ELEMS;
    int ks = r2 >> 9;
    int r3 = r2 & 511;
    int ln = r3 >> 3;
    int j  = r3 & 7;
    int q  = ln >> 4;
    int l15 = ln & 15;
    int n = tile * 16 + l15;
    int k = ks * 32 + q * 8 + j;
    float v = (n < HID && k < HID) ? ldf(w_hid, (l * HID + k) * HID + n, isbf) : 0.f;
    g_wph[t] = (_Float16)v;
  }
  if (t < 8) g_ctr[t] = 0;
  if (t < 64) {  // zero act tail pads (k-overflow reads must not be NaN)
    g_actA[(size_t)N_NODES * APITCH + t] = (_Float16)0.f;
    g_actB[(size_t)N_NODES * APITCH + t] = (_Float16)0.f;
  }
}

// ---- K2a: gather x[src] -> linear g_ev (XCD-local L2 replica) ----
__global__ void gather_kernel(const int* __restrict__ ei) {
  int t = blockIdx.x * blockDim.x + threadIdx.x;   // 800K threads
  int e = t * 8;
  int xcc;
  asm volatile("s_getreg_b32 %0, hwreg(HW_REG_XCC_ID)" : "=s"(xcc));
  const float* xf = g_xf8 + (size_t)(xcc & (NREP - 1)) * N_NODES;
  bool is64 = ((ei[1] | ei[3] | ei[5] | ei[7]) == 0);
  int s[8];
  if (is64) {
#pragma unroll
    for (int i = 0; i < 4; ++i) {
      int4 a = *(const int4*)(ei + 2 * e + 4 * i);
      s[2 * i] = a.x; s[2 * i + 1] = a.z;
    }
  } else {
#pragma unroll
    for (int i = 0; i < 2; ++i) {
      int4 a = *(const int4*)(ei + e + 4 * i);
      s[4 * i] = a.x; s[4 * i + 1] = a.y; s[4 * i + 2] = a.z; s[4 * i + 3] = a.w;
    }
  }
  float v[8];
#pragma unroll
  for (int i = 0; i < 8; ++i) v[i] = xf[s[i]];
  *(float4*)(g_ev + e) = (float4){v[0], v[1], v[2], v[3]};
  *(float4*)(g_ev + e + 4) = (float4){v[4], v[5], v[6], v[7]};
}

// ---- K2b: partitioned scatter via LDS atomics; ZERO global atomics.
// Block (p, c): scan chunk c, ds_add_f32 edges with dst in partition p,
// flush private slice. Streams re-read NPART times -> L3-served. ----
__global__ __launch_bounds__(256) void apply_kernel(const int* __restrict__ ei) {
  extern __shared__ float part[];   // PNODES floats = 80 KB
  const int tid = threadIdx.x;
  const int p = blockIdx.x / PBLK;
  const int cb = blockIdx.x - p * PBLK;
  const int lo = p * PNODES;
  float4* pv = (float4*)part;
  for (int c = tid; c < PNODES / 4; c += 256) pv[c] = (float4){0.f, 0.f, 0.f, 0.f};
  __syncthreads();
  const bool is64 = ((ei[1] | ei[3] | ei[5] | ei[7]) == 0);
  const int base = cb * CHUNK_E;
  for (int g = 0; g < CHUNK_E / (256 * 4); ++g) {   // 125 iterations
    int idx = base + (g * 256 + tid) * 4;
    float4 v = *(const float4*)(g_ev + idx);
    int d0, d1, d2, d3;
    if (is64) {
      int4 b0 = *(const int4*)(ei + 2 * (size_t)N_EDGES + 2 * (size_t)idx);
      int4 b1 = *(const int4*)(ei + 2 * (size_t)N_EDGES + 2 * (size_t)idx + 4);
      d0 = b0.x; d1 = b0.z; d2 = b1.x; d3 = b1.z;
    } else {
      int4 b = *(const int4*)(ei + N_EDGES + idx);
      d0 = b.x; d1 = b.y; d2 = b.z; d3 = b.w;
    }
    unsigned u0 = (unsigned)(d0 - lo), u1 = (unsigned)(d1 - lo);
    unsigned u2 = (unsigned)(d2 - lo), u3 = (unsigned)(d3 - lo);
    if (u0 < PNODES) __hip_atomic_fetch_add(&part[u0], v.x, __ATOMIC_RELAXED, __HIP_MEMORY_SCOPE_WORKGROUP);
    if (u1 < PNODES) __hip_atomic_fetch_add(&part[u1], v.y, __ATOMIC_RELAXED, __HIP_MEMORY_SCOPE_WORKGROUP);
    if (u2 < PNODES) __hip_atomic_fetch_add(&part[u2], v.z, __ATOMIC_RELAXED, __HIP_MEMORY_SCOPE_WORKGROUP);
    if (u3 < PNODES) __hip_atomic_fetch_add(&part[u3], v.w, __ATOMIC_RELAXED, __HIP_MEMORY_SCOPE_WORKGROUP);
  }
  __syncthreads();
  float* gp = g_part + (size_t)blockIdx.x * PNODES;
  for (int c = tid; c < PNODES / 4; c += 256)
    *(float4*)(gp + c * 4) = pv[c];
}

// ---- K2c: reduce slices -> g_agg (coalesced; no atomics) ----
__global__ void reduce_kernel() {
  int n = blockIdx.x * 256 + threadIdx.x;
  if (n >= N_NODES) return;
  int p = n / PNODES;
  int off = n - p * PNODES;
  const float* base = g_part + (size_t)p * PBLK * PNODES + off;
  float s = 0.f;
#pragma unroll
  for (int c = 0; c < PBLK; ++c) s += base[(size_t)c * PNODES];
  g_agg[n] = s;
}

// ---- K3: GraphConv + input layer -> g_actA ----
__global__ void input_kernel(const void* __restrict__ w_rel, const void* __restrict__ b_rel,
                             const void* __restrict__ w_root, const void* __restrict__ w_in,
                             const void* __restrict__ b_in) {
  __shared__ float sw[HID], sb[HID];
  int tid = threadIdx.x;
  int isbf = g_isbf;
  for (int i = tid; i < HID; i += 512) { sw[i] = ldf(w_in, i, isbf); sb[i] = ldf(b_in, i, isbf); }
  __syncthreads();
  int node = blockIdx.x * 512 + tid;
  if (node >= N_NODES) return;
  float h0 = g_agg[node] * ldf(w_rel, 0, isbf) + ldf(b_rel, 0, isbf) +
             g_xf8[node] * ldf(w_root, 0, isbf);
  _Float16* ar = g_actA + (size_t)node * APITCH;
#pragma unroll
  for (int g = 0; g < 26; ++g) {
    f16x8 pv;
#pragma unroll
    for (int j = 0; j < 8; ++j) {
      int col = g * 8 + j;
      float v = (col < HID) ? fmaxf(h0 * sw[col] + sb[col], 0.f) : 0.f;
      pv[j] = (_Float16)v;
    }
    *(f16x8*)(ar + g * 8) = pv;
  }
}

// ---- K4 x6: one hidden layer. Weights LDS-resident (staged once), 8 waves
// x 32-row strips, no barriers in the strip loop. Dynamic strip scheduling
// via g_ctr[l] removes the 4-vs-3.05 strip tail imbalance. ----
__global__ __launch_bounds__(512, 2) void layer_kernel(
    int l, int dir, const void* __restrict__ b_hid) {
  extern __shared__ char smem[];
  _Float16* wl = (_Float16*)smem;
  float* biasl = (float*)(smem + LDS_BIAS);
  const _Float16* ain = dir ? g_actB : g_actA;
  _Float16* aout = dir ? g_actA : g_actB;

  const int tid = threadIdx.x;
  const int isbf = g_isbf;
  const int lane = tid & 63;
  const int wv = tid >> 6;
  const int l15 = lane & 15;
  const int q = lane >> 4;
  const int mode = mfma_selftest(l15, q);

  {  // stage packed layer weights + bias, once
    const _Float16* wg = g_wph + (size_t)l * PL_ELEMS;
    for (int c = tid; c < WCHUNKS; c += 512) load_lds16(wg + c * 8, wl + c * 8);
  }
  for (int i = tid; i < 208; i += 512)
    biasl[i] = (i < HID) ? ldf(b_hid, l * HID + i, isbf) : 0.f;
  __syncthreads();   // drains staging; the ONLY barrier in this kernel

  if (mode < 2) {
    float bias_c[13];
#pragma unroll
    for (int t = 0; t < 13; ++t) bias_c[t] = biasl[t * 16 + l15];

    int s = blockIdx.x * 8 + wv;   // 2048 static waves, then dynamic
    while (s < NSTRIP) {
      const _Float16* ar0 = ain + (size_t)(s * 32 + l15) * APITCH + q * 8;
      const _Float16* ar1 = ar0 + 16 * APITCH;
      f16x8 af0[7], af1[7];
#pragma unroll
      for (int ks = 0; ks < 7; ++ks) {
        af0[ks] = *(const f16x8*)(ar0 + ks * 32);
        af1[ks] = *(const f16x8*)(ar1 + ks * 32);
      }
      f32x4 acc[2][13];
#pragma unroll
      for (int rt = 0; rt < 2; ++rt)
#pragma unroll
        for (int t = 0; t < 13; ++t) acc[rt][t] = (f32x4){0.f, 0.f, 0.f, 0.f};

#pragma unroll
      for (int t = 0; t < 13; ++t)
#pragma unroll
        for (int ks = 0; ks < 7; ++ks) {
          f16x8 b = *(const f16x8*)(wl + ((t * 7 + ks) << 9) + lane * 8);
          acc[0][t] = __builtin_amdgcn_mfma_f32_16x16x32_f16(af0[ks], b, acc[0][t], 0, 0, 0);
          acc[1][t] = __builtin_amdgcn_mfma_f32_16x16x32_f16(af1[ks], b, acc[1][t], 0, 0, 0);
        }

#pragma unroll
      for (int rt = 0; rt < 2; ++rt)
#pragma unroll
        for (int t = 0; t < 13; ++t)
#pragma unroll
          for (int r = 0; r < 4; ++r) {
            int rr = (mode == 0) ? (q * 4 + r) : l15;
            int cc = (mode == 0) ? l15 : (q * 4 + r);
            int row = s * 32 + rt * 16 + rr;
            int col = t * 16 + cc;
            float bv = (mode == 0) ? bias_c[t] : biasl[col];
            float v = acc[rt][t][r] + bv;
            aout[(size_t)row * APITCH + col] = (_Float16)fmaxf(v, 0.f);
          }

      int nxt;
      if (lane == 0) nxt = 2048 + atomicAdd(&g_ctr[l], 1);
      s = __shfl(nxt, 0);
    }
  } else {
    // ---- defensive VALU fallback (static stride; correctness only) ----
    for (int s = blockIdx.x * 8 + wv; s < NSTRIP; s += 2048) {
      int row = s * 32 + (lane & 31);
      const _Float16* ar = ain + (size_t)row * APITCH;
      int j0b = (lane >> 5) * 100;
      for (int j0 = j0b; j0 < j0b + 100; j0 += 2) {
        float a0 = biasl[j0], a1 = biasl[j0 + 1];
        for (int k = 0; k < HID; ++k) {
          float av = (float)ar[k];
          a0 += av * g_wf[(l * HID + k) * HID + j0];
          a1 += av * g_wf[(l * HID + k) * HID + j0 + 1];
        }
        aout[(size_t)row * APITCH + j0] = (_Float16)fmaxf(a0, 0.f);
        aout[(size_t)row * APITCH + j0 + 1] = (_Float16)fmaxf(a1, 0.f);
      }
      if (lane >> 5) {
#pragma unroll
        for (int j = HID; j < APITCH; ++j) aout[(size_t)row * APITCH + j] = (_Float16)0.f;
      }
    }
  }
}

// ---- K5: output layer + sigmoid ----
__global__ void output_kernel(const void* __restrict__ w_out, const void* __restrict__ b_out,
                              void* __restrict__ out) {
  __shared__ float swo[HID];
  int tid = threadIdx.x;
  int isbf = g_isbf;
  for (int i = tid; i < HID; i += 512) swo[i] = ldf(w_out, i, isbf);
  __syncthreads();
  int m = blockIdx.x * 64 + (tid >> 3), c = tid & 7;
  if (m >= N_NODES) return;
  const _Float16* ar = g_actA + (size_t)m * APITCH;
  float s = 0.f;
#pragma unroll
  for (int j = c * 25; j < c * 25 + 25; ++j) s += (float)ar[j] * swo[j];
  s += __shfl_down(s, 4);
  s += __shfl_down(s, 2);
  s += __shfl_down(s, 1);
  if (c == 0) {
    float logit = s + ldf(b_out, 0, isbf);
    float o = 1.f / (1.f + __expf(-logit));
    if (isbf) ((u16*)out)[m] = f2bf(o);
    else ((float*)out)[m] = o;
  }
}

extern "C" void kernel_launch(void* const* d_in, const int* in_sizes, int n_in,
                              void* d_out, int out_size, void* d_ws, size_t ws_size,
                              hipStream_t stream) {
  const void* x      = d_in[0];
  const int* ei      = (const int*)d_in[1];
  const void* w_rel  = d_in[2];
  const void* b_rel  = d_in[3];
  const void* w_root = d_in[4];
  const void* w_in   = d_in[5];
  const void* b_in   = d_in[6];
  const void* w_hid  = d_in[7];
  const void* b_hid  = d_in[8];
  const void* w_out  = d_in[9];
  const void* b_out  = d_in[10];
  (void)d_ws; (void)ws_size; (void)in_sizes; (void)n_in; (void)out_size;

  sniff_kernel<<<1, 64, 0, stream>>>((const u32*)x);
  prep_kernel<<<(NREP * N_NODES + 255) / 256, 256, 0, stream>>>(x, w_hid);
  gather_kernel<<<N_EDGES / 8 / 256, 256, 0, stream>>>(ei);
  apply_kernel<<<NPART * PBLK, 256, APPLY_LDS, stream>>>(ei);
  reduce_kernel<<<(N_NODES + 255) / 256, 256, 0, stream>>>();
  input_kernel<<<(N_NODES + 511) / 512, 512, 0, stream>>>(w_rel, b_rel, w_root, w_in, b_in);
  for (int l = 0; l < 6; ++l)
    layer_kernel<<<256, 512, LDSH_TOTAL, stream>>>(l, l & 1, b_hid);
  output_kernel<<<N_NODES / 64, 512, 0, stream>>>(w_out, b_out, d_out);
}

// Round 6
// 636.695 us; speedup vs baseline: 1.2712x; 1.2712x over previous
//
#include <hip/hip_runtime.h>

#define N_NODES 200000
#define N_EDGES 6400000
#define HID 200
#define NREP 8                    // x-gather replicas (one per XCD)
#define MT 64                     // nodes per block (3125 * 64 = 200000 exactly)
#define ASTR 232                  // act row stride (fp16): 464 B; 2-way bank alias = free
#define AELEM (MT * ASTR)         // 14848 elems = 29696 B
#define WSTR 232
#define WROWS 224
#define WELEMS (WROWS * WSTR)     // g_wph per-layer elems
#define H0ROWS 112                // half0: tiles 0..6
#define H1ROWS 96                 // half1: tiles 7..12
#define H0CH (H0ROWS * WSTR * 2 / 16)   // 3248 16-B chunks
#define H1CH (H1ROWS * WSTR * 2 / 16)   // 2784 16-B chunks

// LDS (mlp): act [0, 29696) ; wlds [29696, 81664) ; h0s aliased at wlds start
// (dead before first stage). 81,664 x 2 blocks = 163,328 <= 163,840 -> 2/CU.
#define LDS_WOFF 29696
#define LDS_TOTAL 81664

// Scatter partitioning (NO global atomics): 20 partitions x 10K nodes.
// 40 KB LDS -> 4 blocks/CU (16 waves, 2x R5 occupancy). 1000 blocks.
#define NPART 20
#define PNODES 10000
#define PBLK 50                   // edge-chunks
#define CHUNK_E (N_EDGES / PBLK)  // 128000 edges, exact
#define APPLY_LDS (PNODES * 4)    // 40000 B

typedef float f32x4 __attribute__((ext_vector_type(4)));
typedef _Float16 f16x8 __attribute__((ext_vector_type(8)));
typedef unsigned short u16;
typedef unsigned int u32;

__device__ __align__(16) float g_agg[N_NODES];           // reduced aggregation
__device__ __align__(16) float g_xf8[NREP * N_NODES];    // fp32 x, per-XCD replica
__device__ __align__(16) float g_wf[6 * HID * HID];      // fp32 (VALU fallback)
__device__ __align__(16) _Float16 g_wph[6 * WELEMS];     // fp16 W^T padded [l][n][k]
__device__ __align__(16) float g_ev[N_EDGES];            // gathered x[src]
__device__ __align__(16) float g_part[NPART * PBLK * PNODES];  // 40 MB slices
__device__ int g_isbf;

__device__ __forceinline__ float bf2f(u16 u) {
  union { u32 i; float f; } v; v.i = ((u32)u) << 16; return v.f;
}
__device__ __forceinline__ u16 f2bf(float f) {  // RNE
  u32 i = __float_as_uint(f);
  return (u16)((i + 0x7FFFu + ((i >> 16) & 1u)) >> 16);
}
__device__ __forceinline__ float ldf(const void* p, int i, int isbf) {
  return isbf ? bf2f(((const u16*)p)[i]) : ((const float*)p)[i];
}
__device__ __forceinline__ void load_lds16(const void* g, void* l) {
  __builtin_amdgcn_global_load_lds(
      (const __attribute__((address_space(1))) u32*)g,
      (__attribute__((address_space(3))) u32*)l, 16, 0, 0);
}

// ---- rank-2 MFMA layout self-test (fp16), reference folded at compile time ----
constexpr int tf1(int m) { return (m & 3) + 1; }
constexpr int tf2(int m) { return ((m >> 2) & 3) + 2; }
constexpr int tg1(int k) { return (k & 7) + 1; }
constexpr int tg2(int k) { return ((k >> 3) & 3) + 1; }
constexpr int tu1(int k) { return ((k * 3) & 7) + 1; }
constexpr int tu2(int k) { return ((k >> 2) & 3) + 2; }
constexpr int tw1(int n) { return ((n * 5) & 7) + 1; }
constexpr int tw2(int n) { return ((n >> 2) & 3) + 1; }
constexpr int calcS(int i, int j) {
  int s = 0;
  for (int k = 0; k < 32; ++k)
    s += (i ? tg2(k) : tg1(k)) * (j ? tu2(k) : tu1(k));
  return s;
}
__device__ __forceinline__ float refD(int m, int n) {
  constexpr int S11 = calcS(0, 0), S12 = calcS(0, 1), S21 = calcS(1, 0), S22 = calcS(1, 1);
  return (float)(tf1(m) * tw1(n) * S11 + tf1(m) * tw2(n) * S12 +
                 tf2(m) * tw1(n) * S21 + tf2(m) * tw2(n) * S22);
}
__device__ int mfma_selftest(int l15, int q) {
  f16x8 av, bv;
#pragma unroll
  for (int j = 0; j < 8; ++j) {
    int k = q * 8 + j;
    av[j] = (_Float16)(float)(tf1(l15) * tg1(k) + tf2(l15) * tg2(k));
    bv[j] = (_Float16)(float)(tu1(k) * tw1(l15) + tu2(k) * tw2(l15));
  }
  f32x4 d = __builtin_amdgcn_mfma_f32_16x16x32_f16(av, bv, (f32x4){0.f, 0.f, 0.f, 0.f}, 0, 0, 0);
  bool ok0 = true, ok1 = true;
#pragma unroll
  for (int r = 0; r < 4; ++r) {
    ok0 = ok0 && (d[r] == refD(q * 4 + r, l15));
    ok1 = ok1 && (d[r] == refD(l15, q * 4 + r));
  }
  return __all(ok0) ? 0 : (__all(ok1) ? 1 : 2);
}

// ---- K0: dtype sniff ----
__global__ void sniff_kernel(const u32* __restrict__ xw) {
  int i = threadIdx.x;  // 64 threads
  u32 e = (xw[i] >> 7) & 0xFFu;
  unsigned long long b = __ballot(e >= 110u && e <= 135u);
  if (i == 0) g_isbf = (__popcll(b) >= 48) ? 1 : 0;
}

// ---- K1: replicate x + both weight forms ----
__global__ void prep_kernel(const void* __restrict__ x, const void* __restrict__ w_hid) {
  int t = blockIdx.x * blockDim.x + threadIdx.x;   // 1.6M threads
  int isbf = g_isbf;
  if (t < NREP * N_NODES) {
    int qd = t / N_NODES;
    int node = t - qd * N_NODES;
    g_xf8[t] = ldf(x, node, isbf);
  }
  if (t < 6 * HID * HID) g_wf[t] = ldf(w_hid, t, isbf);
  if (t < 6 * WELEMS) {
    int l = t / WELEMS;
    int r = t - l * WELEMS;
    int n = r / WSTR;
    int k = r - n * WSTR;
    float v = 0.f;
    if (n < HID && k < HID) v = ldf(w_hid, (l * HID + k) * HID + n, isbf);
    g_wph[t] = (_Float16)v;
  }
}

// ---- K2a: gather x[src] -> linear g_ev (XCD-local L2 replica) ----
__global__ void gather_kernel(const int* __restrict__ ei) {
  int t = blockIdx.x * blockDim.x + threadIdx.x;   // 800K threads
  int e = t * 8;
  int xcc;
  asm volatile("s_getreg_b32 %0, hwreg(HW_REG_XCC_ID)" : "=s"(xcc));
  const float* xf = g_xf8 + (size_t)(xcc & (NREP - 1)) * N_NODES;
  bool is64 = ((ei[1] | ei[3] | ei[5] | ei[7]) == 0);
  int s[8];
  if (is64) {
#pragma unroll
    for (int i = 0; i < 4; ++i) {
      int4 a = *(const int4*)(ei + 2 * e + 4 * i);
      s[2 * i] = a.x; s[2 * i + 1] = a.z;
    }
  } else {
#pragma unroll
    for (int i = 0; i < 2; ++i) {
      int4 a = *(const int4*)(ei + e + 4 * i);
      s[4 * i] = a.x; s[4 * i + 1] = a.y; s[4 * i + 2] = a.z; s[4 * i + 3] = a.w;
    }
  }
  float v[8];
#pragma unroll
  for (int i = 0; i < 8; ++i) v[i] = xf[s[i]];
  *(float4*)(g_ev + e) = (float4){v[0], v[1], v[2], v[3]};
  *(float4*)(g_ev + e + 4) = (float4){v[4], v[5], v[6], v[7]};
}

// ---- K2b: partitioned scatter via LDS atomics; ZERO global atomics.
// Block (p, c): scan chunk c, ds_add edges with dst in partition p, flush
// private slice. 40 KB LDS -> 4 blocks/CU (16 waves; R5 had 8 at 20% occ). ----
__global__ __launch_bounds__(256) void apply_kernel(const int* __restrict__ ei) {
  extern __shared__ float part[];   // PNODES floats = 40 KB
  const int tid = threadIdx.x;
  const int p = blockIdx.x / PBLK;
  const int cb = blockIdx.x - p * PBLK;
  const int lo = p * PNODES;
  float4* pv = (float4*)part;
  for (int c = tid; c < PNODES / 4; c += 256) pv[c] = (float4){0.f, 0.f, 0.f, 0.f};
  __syncthreads();
  const bool is64 = ((ei[1] | ei[3] | ei[5] | ei[7]) == 0);
  const int base = cb * CHUNK_E;
  for (int g = 0; g < CHUNK_E / (256 * 4); ++g) {   // 125 iterations
    int idx = base + (g * 256 + tid) * 4;
    float4 v = *(const float4*)(g_ev + idx);
    int d0, d1, d2, d3;
    if (is64) {
      int4 b0 = *(const int4*)(ei + 2 * (size_t)N_EDGES + 2 * (size_t)idx);
      int4 b1 = *(const int4*)(ei + 2 * (size_t)N_EDGES + 2 * (size_t)idx + 4);
      d0 = b0.x; d1 = b0.z; d2 = b1.x; d3 = b1.z;
    } else {
      int4 b = *(const int4*)(ei + N_EDGES + idx);
      d0 = b.x; d1 = b.y; d2 = b.z; d3 = b.w;
    }
    unsigned u0 = (unsigned)(d0 - lo), u1 = (unsigned)(d1 - lo);
    unsigned u2 = (unsigned)(d2 - lo), u3 = (unsigned)(d3 - lo);
    if (u0 < PNODES) __hip_atomic_fetch_add(&part[u0], v.x, __ATOMIC_RELAXED, __HIP_MEMORY_SCOPE_WORKGROUP);
    if (u1 < PNODES) __hip_atomic_fetch_add(&part[u1], v.y, __ATOMIC_RELAXED, __HIP_MEMORY_SCOPE_WORKGROUP);
    if (u2 < PNODES) __hip_atomic_fetch_add(&part[u2], v.z, __ATOMIC_RELAXED, __HIP_MEMORY_SCOPE_WORKGROUP);
    if (u3 < PNODES) __hip_atomic_fetch_add(&part[u3], v.w, __ATOMIC_RELAXED, __HIP_MEMORY_SCOPE_WORKGROUP);
  }
  __syncthreads();
  float* gp = g_part + (size_t)blockIdx.x * PNODES;
  for (int c = tid; c < PNODES / 4; c += 256)
    *(float4*)(gp + c * 4) = pv[c];
}

// ---- K2c: reduce slices -> g_agg (coalesced; no atomics) ----
__global__ void reduce_kernel() {
  int n = blockIdx.x * 256 + threadIdx.x;
  if (n >= N_NODES) return;
  int p = n / PNODES;
  int off = n - p * PNODES;
  const float* base = g_part + (size_t)p * PBLK * PNODES + off;
  float s = 0.f;
#pragma unroll
  for (int c = 0; c < PBLK; ++c) s += base[(size_t)c * PNODES];
  g_agg[n] = s;
}

// ---- K3: fused MLP (R0-verified structure; 361 us, MfmaUtil 13%).
// MT=64, 512 thr / 8 waves, W in halves, 2 blocks/CU. Only change vs R0:
// h0 reads the single reduced g_agg (scatter now atomics-free). ----
__global__ __launch_bounds__(512, 4) void mlp_kernel(
    const void* __restrict__ w_rel, const void* __restrict__ b_rel, const void* __restrict__ w_root,
    const void* __restrict__ w_in, const void* __restrict__ b_in,
    const void* __restrict__ b_hid, const void* __restrict__ w_out, const void* __restrict__ b_out,
    void* __restrict__ out) {
  extern __shared__ char smem[];
  _Float16* act = (_Float16*)smem;
  _Float16* wlds = (_Float16*)(smem + LDS_WOFF);
  float* h0s = (float*)(smem + LDS_WOFF);  // aliased; dead before first stage

  const int tid = threadIdx.x;
  const int nb = blockIdx.x * MT;
  const int isbf = g_isbf;
  const int lane = tid & 63;
  const int wv = tid >> 6;          // 8 waves
  const int l15 = lane & 15;
  const int q = lane >> 4;
  const int band = wv >> 1;         // 4 bands x 16 rows
  const int cg = wv & 1;            // col group (wave-uniform)

  const int mode = mfma_selftest(l15, q);

  // GraphConv h0
  if (tid < MT) {
    int node = nb + tid;
    h0s[tid] = g_agg[node] * ldf(w_rel, 0, isbf) + ldf(b_rel, 0, isbf) +
               g_xf8[node] * ldf(w_root, 0, isbf);
  }
  __syncthreads();

  if (mode < 2) {
    // Input layer: act[m][j] = relu(h0[m]*w_in[j]+b_in[j]); pad cols zeroed
    for (int idx = tid; idx < AELEM; idx += 512) {
      int m = idx / ASTR, j = idx - m * ASTR;
      float v = 0.f;
      if (j < HID) {
        v = h0s[m] * ldf(w_in, j, isbf) + ldf(b_in, j, isbf);
        v = fmaxf(v, 0.f);
      }
      act[idx] = (_Float16)v;
    }

    for (int l = 0; l < 6; ++l) {
      f32x4 acc[7];
#pragma unroll
      for (int n = 0; n < 7; ++n) acc[n] = (f32x4){0.f, 0.f, 0.f, 0.f};

      const _Float16* ap = act + (band * 16 + l15) * ASTR + q * 8;

      // ---- half 0: global tiles 0..6 staged at local rows 0..111 ----
      __syncthreads();  // act stable, prior wlds reads done
      {
        const _Float16* wg = g_wph + l * WELEMS;
        for (int c = tid; c < H0CH; c += 512) load_lds16(wg + c * 8, wlds + c * 8);
      }
      __syncthreads();  // drain
      if (cg == 0) {    // tiles 0..3 -> acc[0..3] (all indices literal)
        const _Float16* bp = wlds + l15 * WSTR + q * 8;
#pragma unroll
        for (int ks = 0; ks < 7; ++ks) {
          f16x8 a = *(const f16x8*)(ap + ks * 32);
#pragma unroll
          for (int n = 0; n < 4; ++n) {
            f16x8 b = *(const f16x8*)(bp + n * 16 * WSTR + ks * 32);
            acc[n] = __builtin_amdgcn_mfma_f32_16x16x32_f16(a, b, acc[n], 0, 0, 0);
          }
        }
      } else {          // tiles 4..6 -> acc[0..2]
        const _Float16* bp = wlds + (4 * 16 + l15) * WSTR + q * 8;
#pragma unroll
        for (int ks = 0; ks < 7; ++ks) {
          f16x8 a = *(const f16x8*)(ap + ks * 32);
#pragma unroll
          for (int n = 0; n < 3; ++n) {
            f16x8 b = *(const f16x8*)(bp + n * 16 * WSTR + ks * 32);
            acc[n] = __builtin_amdgcn_mfma_f32_16x16x32_f16(a, b, acc[n], 0, 0, 0);
          }
        }
      }

      // ---- half 1: global tiles 7..12 staged at local rows 0..95 ----
      __syncthreads();  // all half-0 B reads done before overwrite
      {
        const _Float16* wg = g_wph + l * WELEMS + H0ROWS * WSTR;
        for (int c = tid; c < H1CH; c += 512) load_lds16(wg + c * 8, wlds + c * 8);
      }
      __syncthreads();  // drain
      if (cg == 0) {    // tiles 7..9 -> acc[4..6]
        const _Float16* bp = wlds + l15 * WSTR + q * 8;
#pragma unroll
        for (int ks = 0; ks < 7; ++ks) {
          f16x8 a = *(const f16x8*)(ap + ks * 32);
#pragma unroll
          for (int n = 0; n < 3; ++n) {
            f16x8 b = *(const f16x8*)(bp + n * 16 * WSTR + ks * 32);
            acc[4 + n] = __builtin_amdgcn_mfma_f32_16x16x32_f16(a, b, acc[4 + n], 0, 0, 0);
          }
        }
      } else {          // tiles 10..12 -> acc[3..5]
        const _Float16* bp = wlds + (3 * 16 + l15) * WSTR + q * 8;
#pragma unroll
        for (int ks = 0; ks < 7; ++ks) {
          f16x8 a = *(const f16x8*)(ap + ks * 32);
#pragma unroll
          for (int n = 0; n < 3; ++n) {
            f16x8 b = *(const f16x8*)(bp + n * 16 * WSTR + ks * 32);
            acc[3 + n] = __builtin_amdgcn_mfma_f32_16x16x32_f16(a, b, acc[3 + n], 0, 0, 0);
          }
        }
      }
      __syncthreads();  // all act/wlds reads done before in-place act writes

      // epilogue: bias + relu, in-place fp16 (all acc indices literal)
      if (cg == 0) {    // acc[0..3]->tiles 0..3, acc[4..6]->tiles 7..9
#pragma unroll
        for (int i = 0; i < 7; ++i) {
          const int gt = (i < 4) ? i : 3 + i;   // 0,1,2,3,7,8,9 (i literal)
          const int ctile = gt * 16;
#pragma unroll
          for (int r = 0; r < 4; ++r) {
            int rr = (mode == 0) ? (q * 4 + r) : l15;
            int cc = (mode == 0) ? l15 : (q * 4 + r);
            int row = band * 16 + rr, col = ctile + cc;
            float v = acc[i][r] + ((col < HID) ? ldf(b_hid, l * HID + col, isbf) : 0.f);
            act[row * ASTR + col] = (_Float16)fmaxf(v, 0.f);
          }
        }
      } else {          // acc[0..2]->tiles 4..6, acc[3..5]->tiles 10..12
#pragma unroll
        for (int i = 0; i < 6; ++i) {
          const int gt = (i < 3) ? 4 + i : 7 + i;  // 4,5,6,10,11,12
          const int ctile = gt * 16;
#pragma unroll
          for (int r = 0; r < 4; ++r) {
            int rr = (mode == 0) ? (q * 4 + r) : l15;
            int cc = (mode == 0) ? l15 : (q * 4 + r);
            int row = band * 16 + rr, col = ctile + cc;
            float v = acc[i][r] + ((col < HID) ? ldf(b_hid, l * HID + col, isbf) : 0.f);
            act[row * ASTR + col] = (_Float16)fmaxf(v, 0.f);
          }
        }
      }
    }

    __syncthreads();
    // Output layer: 8 threads/row x 25 cols
    {
      int m = tid >> 3, c = tid & 7;
      const _Float16* ar = act + m * ASTR;
      float s = 0.f;
#pragma unroll
      for (int j = c * 25; j < c * 25 + 25; ++j)
        s += (float)ar[j] * ldf(w_out, j, isbf);
      s += __shfl_down(s, 4);
      s += __shfl_down(s, 2);
      s += __shfl_down(s, 1);
      if (c == 0) {
        float logit = s + ldf(b_out, 0, isbf);
        float o = 1.f / (1.f + __expf(-logit));
        if (isbf) ((u16*)out)[nb + m] = f2bf(o);
        else ((float*)out)[nb + m] = o;
      }
    }
  } else {
    // ---- VALU fallback (defensive; 2 passes of 32 rows) ----
    float(*fA)[201] = (float(*)[201])smem;                    // 32x201 fp32
    float(*fB)[201] = (float(*)[201])(smem + 32 * 201 * 4);
    float* h0f = (float*)(smem + 64 * 201 * 4);
    for (int p = 0; p < 2; ++p) {
      __syncthreads();
      if (tid < 32) {
        int node = nb + p * 32 + tid;
        h0f[tid] = g_agg[node] * ldf(w_rel, 0, isbf) + ldf(b_rel, 0, isbf) +
                   g_xf8[node] * ldf(w_root, 0, isbf);
      }
      __syncthreads();
      for (int i = tid; i < 32 * HID; i += 512) {
        int mm = i / HID, ff = i - mm * HID;
        float v = h0f[mm] * ldf(w_in, ff, isbf) + ldf(b_in, ff, isbf);
        fA[mm][ff] = v > 0.f ? v : 0.f;
      }
      __syncthreads();
      const int m = tid >> 4, c = tid & 15;
      float(*ain)[201] = fA;
      float(*aout)[201] = fB;
      for (int l = 0; l < 6; ++l) {
        float acc[13];
#pragma unroll
        for (int jj = 0; jj < 13; ++jj) {
          int j = c * 13 + jj;
          acc[jj] = (j < HID) ? ldf(b_hid, l * HID + j, isbf) : 0.f;
        }
        const float* wl = g_wf + l * HID * HID;
        for (int k = 0; k < HID; ++k) {
          float a = ain[m][k];
          const float* wr = wl + k * HID;
#pragma unroll
          for (int jj = 0; jj < 13; ++jj) {
            int j = c * 13 + jj;
            if (j < HID) acc[jj] = fmaf(a, wr[j], acc[jj]);
          }
        }
        __syncthreads();
#pragma unroll
        for (int jj = 0; jj < 13; ++jj) {
          int j = c * 13 + jj;
          if (j < HID) aout[m][j] = fmaxf(acc[jj], 0.f);
        }
        float(*tsw)[201] = ain; ain = aout; aout = tsw;
        __syncthreads();
      }
      float s = 0.f;
      for (int j = c * 13; j < c * 13 + 13 && j < HID; ++j)
        s += ain[m][j] * ldf(w_out, j, isbf);
      s += __shfl_down(s, 8);
      s += __shfl_down(s, 4);
      s += __shfl_down(s, 2);
      s += __shfl_down(s, 1);
      int node = nb + p * 32 + m;
      if (c == 0) {
        float logit = s + ldf(b_out, 0, isbf);
        float o = 1.f / (1.f + __expf(-logit));
        if (isbf) ((u16*)out)[node] = f2bf(o);
        else ((float*)out)[node] = o;
      }
    }
  }
}

extern "C" void kernel_launch(void* const* d_in, const int* in_sizes, int n_in,
                              void* d_out, int out_size, void* d_ws, size_t ws_size,
                              hipStream_t stream) {
  const void* x      = d_in[0];
  const int* ei      = (const int*)d_in[1];
  const void* w_rel  = d_in[2];
  const void* b_rel  = d_in[3];
  const void* w_root = d_in[4];
  const void* w_in   = d_in[5];
  const void* b_in   = d_in[6];
  const void* w_hid  = d_in[7];
  const void* b_hid  = d_in[8];
  const void* w_out  = d_in[9];
  const void* b_out  = d_in[10];
  (void)d_ws; (void)ws_size; (void)in_sizes; (void)n_in; (void)out_size;

  sniff_kernel<<<1, 64, 0, stream>>>((const u32*)x);
  prep_kernel<<<(NREP * N_NODES + 255) / 256, 256, 0, stream>>>(x, w_hid);
  gather_kernel<<<N_EDGES / 8 / 256, 256, 0, stream>>>(ei);
  apply_kernel<<<NPART * PBLK, 256, APPLY_LDS, stream>>>(ei);
  reduce_kernel<<<(N_NODES + 255) / 256, 256, 0, stream>>>();
  mlp_kernel<<<N_NODES / MT, 512, LDS_TOTAL, stream>>>(
      w_rel, b_rel, w_root, w_in, b_in, b_hid, w_out, b_out, d_out);
}

// Round 7
// 589.936 us; speedup vs baseline: 1.3720x; 1.0793x over previous
//
#include <hip/hip_runtime.h>

#define N_NODES 200000
#define N_EDGES 6400000
#define HID 200
#define NREP 8                    // x-gather replicas (one per XCD)
#define MT 64                     // nodes per block (3125 * 64 = 200000 exactly)

// Packed fragment layouts for mfma_f32_32x32x16_f16 (frag = 1KB contiguous):
//   A: actp[band 2][ks 14][lane 64][j 8]; elem = act(row = band*32+(lane&31),
//      k = ks*16 + (lane>>5)*8 + j)
//   B: g_wpk[l][kh 2][tile 7][ks7 7][lane 64][j 8]; elem = W^T(n = tile*32+
//      (lane&31), k = (kh*7+ks7)*16 + (lane>>5)*8 + j), zero-padded
#define PK_ELEMS (7 * 14 * 512)   // 50176 elems = 100352 B per layer
#define PK_HALF  (PK_ELEMS / 2)   // 25088 elems = 50176 B per k-half
#define STG_CHUNKS (PK_HALF * 2 / 16)  // 3136 16-B staging chunks

// LDS (mlp): actp [0, 28672) ; wbuf [28672, 78848) ; h0s [78848, 79104)
// 79,104 x 2 blocks = 158,208 <= 163,840 -> 2 blocks/CU.
#define LDS_WOFF 28672
#define LDS_H0S  78848
#define LDS_TOTAL 79104

// Scatter partitioning (NO global atomics): 20 partitions x 10K nodes.
#define NPART 20
#define PNODES 10000
#define PBLK 50                   // edge-chunks
#define CHUNK_E (N_EDGES / PBLK)  // 128000 edges, exact
#define APPLY_LDS (PNODES * 4)    // 40000 B

typedef float f32x4 __attribute__((ext_vector_type(4)));
typedef float f32x16 __attribute__((ext_vector_type(16)));
typedef _Float16 f16x8 __attribute__((ext_vector_type(8)));
typedef unsigned short u16;
typedef unsigned int u32;

__device__ __align__(16) float g_agg[N_NODES];           // reduced aggregation
__device__ __align__(16) float g_xf8[NREP * N_NODES];    // fp32 x, per-XCD replica
__device__ __align__(16) float g_wf[6 * HID * HID];      // fp32 (VALU fallback)
__device__ __align__(16) _Float16 g_wpk[6 * PK_ELEMS];   // packed W^T frags
__device__ __align__(16) float g_ev[N_EDGES];            // gathered x[src]
__device__ __align__(16) float g_part[NPART * PBLK * PNODES];  // 40 MB slices
__device__ int g_isbf;

__device__ __forceinline__ float bf2f(u16 u) {
  union { u32 i; float f; } v; v.i = ((u32)u) << 16; return v.f;
}
__device__ __forceinline__ u16 f2bf(float f) {  // RNE
  u32 i = __float_as_uint(f);
  return (u16)((i + 0x7FFFu + ((i >> 16) & 1u)) >> 16);
}
__device__ __forceinline__ float ldf(const void* p, int i, int isbf) {
  return isbf ? bf2f(((const u16*)p)[i]) : ((const float*)p)[i];
}
__device__ __forceinline__ void load_lds16(const void* g, void* l) {
  __builtin_amdgcn_global_load_lds(
      (const __attribute__((address_space(1))) u32*)g,
      (__attribute__((address_space(3))) u32*)l, 16, 0, 0);
}

// ---- rank-2 MFMA layout self-test for 32x32x16_f16, compile-time ref ----
constexpr int sf1(int m) { return (m & 7) + 1; }
constexpr int sf2(int m) { return ((m >> 3) & 3) + 2; }
constexpr int sg1(int k) { return (k & 7) + 1; }
constexpr int sg2(int k) { return ((k >> 3) & 1) + 1; }
constexpr int su1(int k) { return ((k * 3) & 7) + 1; }
constexpr int su2(int k) { return ((k >> 2) & 3) + 2; }
constexpr int sw1(int n) { return ((n * 5) & 7) + 1; }
constexpr int sw2(int n) { return ((n >> 3) & 3) + 1; }
constexpr int calcS32(int i, int j) {
  int s = 0;
  for (int k = 0; k < 16; ++k)
    s += (i ? sg2(k) : sg1(k)) * (j ? su2(k) : su1(k));
  return s;
}
__device__ __forceinline__ float refD32(int m, int n) {
  constexpr int S11 = calcS32(0, 0), S12 = calcS32(0, 1), S21 = calcS32(1, 0), S22 = calcS32(1, 1);
  return (float)(sf1(m) * sw1(n) * S11 + sf1(m) * sw2(n) * S12 +
                 sf2(m) * sw1(n) * S21 + sf2(m) * sw2(n) * S22);
}
__device__ int mfma_selftest32(int lane) {
  const int m = lane & 31, kh = lane >> 5;
  f16x8 av, bv;
#pragma unroll
  for (int j = 0; j < 8; ++j) {
    int k = kh * 8 + j;
    av[j] = (_Float16)(float)(sf1(m) * sg1(k) + sf2(m) * sg2(k));
    bv[j] = (_Float16)(float)(su1(k) * sw1(m) + su2(k) * sw2(m));
  }
  f32x16 z;
#pragma unroll
  for (int i = 0; i < 16; ++i) z[i] = 0.f;
  f32x16 d = __builtin_amdgcn_mfma_f32_32x32x16_f16(av, bv, z, 0, 0, 0);
  bool ok0 = true, ok1 = true;
#pragma unroll
  for (int reg = 0; reg < 16; ++reg) {
    int rr = (reg & 3) + 8 * (reg >> 2) + 4 * kh;
    ok0 = ok0 && (d[reg] == refD32(rr, m));
    ok1 = ok1 && (d[reg] == refD32(m, rr));
  }
  return __all(ok0) ? 0 : (__all(ok1) ? 1 : 2);
}

// ---- K0: dtype sniff ----
__global__ void sniff_kernel(const u32* __restrict__ xw) {
  int i = threadIdx.x;  // 64 threads
  u32 e = (xw[i] >> 7) & 0xFFu;
  unsigned long long b = __ballot(e >= 110u && e <= 135u);
  if (i == 0) g_isbf = (__popcll(b) >= 48) ? 1 : 0;
}

// ---- K1: replicate x + packed weights + fallback weights ----
__global__ void prep_kernel(const void* __restrict__ x, const void* __restrict__ w_hid) {
  int t = blockIdx.x * blockDim.x + threadIdx.x;   // 1.6M threads
  int isbf = g_isbf;
  if (t < NREP * N_NODES) {
    int qd = t / N_NODES;
    int node = t - qd * N_NODES;
    g_xf8[t] = ldf(x, node, isbf);
  }
  if (t < 6 * HID * HID) g_wf[t] = ldf(w_hid, t, isbf);
  if (t < 6 * PK_ELEMS) {
    int l = t / PK_ELEMS;
    int r = t - l * PK_ELEMS;
    int h = r / PK_HALF;
    int r2 = r - h * PK_HALF;
    int tile = r2 / 3584;            // 7*512 elems per (tile) within half
    int r3 = r2 - tile * 3584;
    int ks7 = r3 >> 9;
    int r4 = r3 & 511;
    int ln = r4 >> 3;
    int j = r4 & 7;
    int n = tile * 32 + (ln & 31);
    int k = (h * 7 + ks7) * 16 + (ln >> 5) * 8 + j;
    float v = (n < HID && k < HID) ? ldf(w_hid, (l * HID + k) * HID + n, isbf) : 0.f;
    g_wpk[t] = (_Float16)v;
  }
}

// ---- K2a: gather x[src] -> linear g_ev (XCD-local L2 replica) ----
__global__ void gather_kernel(const int* __restrict__ ei) {
  int t = blockIdx.x * blockDim.x + threadIdx.x;   // 800K threads
  int e = t * 8;
  int xcc;
  asm volatile("s_getreg_b32 %0, hwreg(HW_REG_XCC_ID)" : "=s"(xcc));
  const float* xf = g_xf8 + (size_t)(xcc & (NREP - 1)) * N_NODES;
  bool is64 = ((ei[1] | ei[3] | ei[5] | ei[7]) == 0);
  int s[8];
  if (is64) {
#pragma unroll
    for (int i = 0; i < 4; ++i) {
      int4 a = *(const int4*)(ei + 2 * e + 4 * i);
      s[2 * i] = a.x; s[2 * i + 1] = a.z;
    }
  } else {
#pragma unroll
    for (int i = 0; i < 2; ++i) {
      int4 a = *(const int4*)(ei + e + 4 * i);
      s[4 * i] = a.x; s[4 * i + 1] = a.y; s[4 * i + 2] = a.z; s[4 * i + 3] = a.w;
    }
  }
  float v[8];
#pragma unroll
  for (int i = 0; i < 8; ++i) v[i] = xf[s[i]];
  *(float4*)(g_ev + e) = (float4){v[0], v[1], v[2], v[3]};
  *(float4*)(g_ev + e + 4) = (float4){v[4], v[5], v[6], v[7]};
}

// ---- K2b: partitioned scatter via LDS atomics; ZERO global atomics ----
__global__ __launch_bounds__(256) void apply_kernel(const int* __restrict__ ei) {
  extern __shared__ float part[];   // PNODES floats = 40 KB
  const int tid = threadIdx.x;
  const int p = blockIdx.x / PBLK;
  const int cb = blockIdx.x - p * PBLK;
  const int lo = p * PNODES;
  float4* pv = (float4*)part;
  for (int c = tid; c < PNODES / 4; c += 256) pv[c] = (float4){0.f, 0.f, 0.f, 0.f};
  __syncthreads();
  const bool is64 = ((ei[1] | ei[3] | ei[5] | ei[7]) == 0);
  const int base = cb * CHUNK_E;
  for (int g = 0; g < CHUNK_E / (256 * 4); ++g) {   // 125 iterations
    int idx = base + (g * 256 + tid) * 4;
    float4 v = *(const float4*)(g_ev + idx);
    int d0, d1, d2, d3;
    if (is64) {
      int4 b0 = *(const int4*)(ei + 2 * (size_t)N_EDGES + 2 * (size_t)idx);
      int4 b1 = *(const int4*)(ei + 2 * (size_t)N_EDGES + 2 * (size_t)idx + 4);
      d0 = b0.x; d1 = b0.z; d2 = b1.x; d3 = b1.z;
    } else {
      int4 b = *(const int4*)(ei + N_EDGES + idx);
      d0 = b.x; d1 = b.y; d2 = b.z; d3 = b.w;
    }
    unsigned u0 = (unsigned)(d0 - lo), u1 = (unsigned)(d1 - lo);
    unsigned u2 = (unsigned)(d2 - lo), u3 = (unsigned)(d3 - lo);
    if (u0 < PNODES) __hip_atomic_fetch_add(&part[u0], v.x, __ATOMIC_RELAXED, __HIP_MEMORY_SCOPE_WORKGROUP);
    if (u1 < PNODES) __hip_atomic_fetch_add(&part[u1], v.y, __ATOMIC_RELAXED, __HIP_MEMORY_SCOPE_WORKGROUP);
    if (u2 < PNODES) __hip_atomic_fetch_add(&part[u2], v.z, __ATOMIC_RELAXED, __HIP_MEMORY_SCOPE_WORKGROUP);
    if (u3 < PNODES) __hip_atomic_fetch_add(&part[u3], v.w, __ATOMIC_RELAXED, __HIP_MEMORY_SCOPE_WORKGROUP);
  }
  __syncthreads();
  float* gp = g_part + (size_t)blockIdx.x * PNODES;
  for (int c = tid; c < PNODES / 4; c += 256)
    *(float4*)(gp + c * 4) = pv[c];
}

// ---- K2c: reduce slices -> g_agg (coalesced; no atomics) ----
__global__ void reduce_kernel() {
  int n = blockIdx.x * 256 + threadIdx.x;
  if (n >= N_NODES) return;
  int p = n / PNODES;
  int off = n - p * PNODES;
  const float* base = g_part + (size_t)p * PBLK * PNODES + off;
  float s = 0.f;
#pragma unroll
  for (int c = 0; c < PBLK; ++c) s += base[(size_t)c * PNODES];
  g_agg[n] = s;
}

// ---- K3: fused MLP with 32x32x16 MFMA (2x FLOP per LDS byte vs 16x16x32).
// R0 skeleton: MT=64, 512 thr / 8 waves, stage K-halves, 2 blocks/CU, 5
// barriers/layer. 8 waves = 2 bands(32 rows) x 4 cgs over 7 n-tiles of 32
// (tiles 2/2/2/1). A and B both read as CONTIGUOUS 1KB packed fragments
// (zero conflicts, base+lane*16B). Per block-layer LDS reads: 314 KB vs
// R0's 514 KB + 3.7e7 conflicts. acc = 2 x f32x16; all indices literal. ----
__global__ __launch_bounds__(512, 4) void mlp_kernel(
    const void* __restrict__ w_rel, const void* __restrict__ b_rel, const void* __restrict__ w_root,
    const void* __restrict__ w_in, const void* __restrict__ b_in,
    const void* __restrict__ b_hid, const void* __restrict__ w_out, const void* __restrict__ b_out,
    void* __restrict__ out) {
  extern __shared__ char smem[];
  _Float16* actp = (_Float16*)smem;
  _Float16* wbuf = (_Float16*)(smem + LDS_WOFF);
  float* h0s = (float*)(smem + LDS_H0S);

  const int tid = threadIdx.x;
  const int nb = blockIdx.x * MT;
  const int isbf = g_isbf;
  const int lane = tid & 63;
  const int wv = tid >> 6;          // 8 waves
  const int band = wv >> 2;         // 2 bands x 32 rows
  const int cg = wv & 3;            // 4 col groups
  const int t0 = cg * 2;            // first n-tile (cg3 owns only tile 6)

  const int mode = mfma_selftest32(lane);

  // GraphConv h0
  if (tid < MT) {
    int node = nb + tid;
    h0s[tid] = g_agg[node] * ldf(w_rel, 0, isbf) + ldf(b_rel, 0, isbf) +
               g_xf8[node] * ldf(w_root, 0, isbf);
  }
  __syncthreads();

  if (mode < 2) {
    // Input layer -> packed A layout; cols >= HID zeroed.
    // u -> (m 0..63, g 0..27): ks = g>>1, kh = g&1, cols = ks*16+kh*8+0..7
    for (int u = tid; u < MT * 28; u += 512) {
      int m = u / 28, g = u - m * 28;
      int ks = g >> 1, kh = g & 1;
      float h0v = h0s[m];
      f16x8 pv;
#pragma unroll
      for (int j = 0; j < 8; ++j) {
        int col = ks * 16 + kh * 8 + j;
        float v = 0.f;
        if (col < HID) v = fmaxf(h0v * ldf(w_in, col, isbf) + ldf(b_in, col, isbf), 0.f);
        pv[j] = (_Float16)v;
      }
      *(f16x8*)(actp + ((m >> 5) * 14 + ks) * 512 + (kh * 32 + (m & 31)) * 8) = pv;
    }

    for (int l = 0; l < 6; ++l) {
      f32x16 acc0, acc1;
#pragma unroll
      for (int i = 0; i < 16; ++i) { acc0[i] = 0.f; acc1[i] = 0.f; }

#pragma unroll
      for (int h = 0; h < 2; ++h) {
        __syncthreads();  // h=0: act stable + prior wbuf reads done; h=1: B-h0 reads done
        {
          const _Float16* wg = g_wpk + (size_t)l * PK_ELEMS + h * PK_HALF;
          for (int c = tid; c < STG_CHUNKS; c += 512) load_lds16(wg + c * 8, wbuf + c * 8);
        }
        __syncthreads();  // drain staging

        f16x8 af[7];
#pragma unroll
        for (int i = 0; i < 7; ++i)
          af[i] = *(const f16x8*)(actp + (band * 14 + h * 7 + i) * 512 + lane * 8);

        if (cg < 3) {
#pragma unroll
          for (int i = 0; i < 7; ++i) {
            f16x8 b0 = *(const f16x8*)(wbuf + (t0 * 7 + i) * 512 + lane * 8);
            f16x8 b1 = *(const f16x8*)(wbuf + ((t0 + 1) * 7 + i) * 512 + lane * 8);
            acc0 = __builtin_amdgcn_mfma_f32_32x32x16_f16(af[i], b0, acc0, 0, 0, 0);
            acc1 = __builtin_amdgcn_mfma_f32_32x32x16_f16(af[i], b1, acc1, 0, 0, 0);
          }
        } else {
#pragma unroll
          for (int i = 0; i < 7; ++i) {
            f16x8 b0 = *(const f16x8*)(wbuf + (6 * 7 + i) * 512 + lane * 8);
            acc0 = __builtin_amdgcn_mfma_f32_32x32x16_f16(af[i], b0, acc0, 0, 0, 0);
          }
        }
      }
      __syncthreads();  // all A/B reads done before in-place actp writes

      // epilogue: bias + relu -> packed A layout for next layer
      if (mode == 0) {
        const int c0 = lane & 31, kh = lane >> 5;
        {
          int col = t0 * 32 + c0;
          float bias = (col < HID) ? ldf(b_hid, l * HID + col, isbf) : 0.f;
          _Float16* dst = actp + (band * 14 + (col >> 4)) * 512 +
                          ((col >> 3) & 1) * 256 + (col & 7);
#pragma unroll
          for (int reg = 0; reg < 16; ++reg) {
            int rr = (reg & 3) + 8 * (reg >> 2) + 4 * kh;
            dst[rr * 8] = (_Float16)fmaxf(acc0[reg] + bias, 0.f);
          }
        }
        if (cg < 3) {
          int col = (t0 + 1) * 32 + c0;
          float bias = (col < HID) ? ldf(b_hid, l * HID + col, isbf) : 0.f;
          _Float16* dst = actp + (band * 14 + (col >> 4)) * 512 +
                          ((col >> 3) & 1) * 256 + (col & 7);
#pragma unroll
          for (int reg = 0; reg < 16; ++reg) {
            int rr = (reg & 3) + 8 * (reg >> 2) + 4 * kh;
            dst[rr * 8] = (_Float16)fmaxf(acc1[reg] + bias, 0.f);
          }
        }
      } else {  // mode 1: transposed D
        const int rr = lane & 31, kh = lane >> 5;
#pragma unroll
        for (int reg = 0; reg < 16; ++reg) {
          int cc = (reg & 3) + 8 * (reg >> 2) + 4 * kh;
          {
            int col = t0 * 32 + cc;
            float v = acc0[reg] + ((col < HID) ? ldf(b_hid, l * HID + col, isbf) : 0.f);
            actp[(band * 14 + (col >> 4)) * 512 + (((col >> 3) & 1) * 32 + rr) * 8 + (col & 7)] =
                (_Float16)fmaxf(v, 0.f);
          }
          if (cg < 3) {
            int col = (t0 + 1) * 32 + cc;
            float v = acc1[reg] + ((col < HID) ? ldf(b_hid, l * HID + col, isbf) : 0.f);
            actp[(band * 14 + (col >> 4)) * 512 + (((col >> 3) & 1) * 32 + rr) * 8 + (col & 7)] =
                (_Float16)fmaxf(v, 0.f);
          }
        }
      }
    }

    __syncthreads();
    // Output layer: 8 threads/row x 25 cols, packed-A addressing
    {
      int m = tid >> 3, c = tid & 7;
      const int mb = (m >> 5) * 14, ml = m & 31;
      float s = 0.f;
#pragma unroll
      for (int j = c * 25; j < c * 25 + 25; ++j) {
        _Float16 a = actp[(mb + (j >> 4)) * 512 + (((j >> 3) & 1) * 32 + ml) * 8 + (j & 7)];
        s += (float)a * ldf(w_out, j, isbf);
      }
      s += __shfl_down(s, 4);
      s += __shfl_down(s, 2);
      s += __shfl_down(s, 1);
      if (c == 0) {
        float logit = s + ldf(b_out, 0, isbf);
        float o = 1.f / (1.f + __expf(-logit));
        if (isbf) ((u16*)out)[nb + m] = f2bf(o);
        else ((float*)out)[nb + m] = o;
      }
    }
  } else {
    // ---- VALU fallback (defensive; 2 passes of 32 rows) ----
    float(*fA)[201] = (float(*)[201])smem;                    // 32x201 fp32
    float(*fB)[201] = (float(*)[201])(smem + 32 * 201 * 4);
    float* h0f = (float*)(smem + 64 * 201 * 4);
    for (int p = 0; p < 2; ++p) {
      __syncthreads();
      if (tid < 32) {
        int node = nb + p * 32 + tid;
        h0f[tid] = g_agg[node] * ldf(w_rel, 0, isbf) + ldf(b_rel, 0, isbf) +
                   g_xf8[node] * ldf(w_root, 0, isbf);
      }
      __syncthreads();
      for (int i = tid; i < 32 * HID; i += 512) {
        int mm = i / HID, ff = i - mm * HID;
        float v = h0f[mm] * ldf(w_in, ff, isbf) + ldf(b_in, ff, isbf);
        fA[mm][ff] = v > 0.f ? v : 0.f;
      }
      __syncthreads();
      const int m = tid >> 4, c = tid & 15;
      float(*ain)[201] = fA;
      float(*aout)[201] = fB;
      for (int l = 0; l < 6; ++l) {
        float acc[13];
#pragma unroll
        for (int jj = 0; jj < 13; ++jj) {
          int j = c * 13 + jj;
          acc[jj] = (j < HID) ? ldf(b_hid, l * HID + j, isbf) : 0.f;
        }
        const float* wl = g_wf + l * HID * HID;
        for (int k = 0; k < HID; ++k) {
          float a = ain[m][k];
          const float* wr = wl + k * HID;
#pragma unroll
          for (int jj = 0; jj < 13; ++jj) {
            int j = c * 13 + jj;
            if (j < HID) acc[jj] = fmaf(a, wr[j], acc[jj]);
          }
        }
        __syncthreads();
#pragma unroll
        for (int jj = 0; jj < 13; ++jj) {
          int j = c * 13 + jj;
          if (j < HID) aout[m][j] = fmaxf(acc[jj], 0.f);
        }
        float(*tsw)[201] = ain; ain = aout; aout = tsw;
        __syncthreads();
      }
      float s = 0.f;
      for (int j = c * 13; j < c * 13 + 13 && j < HID; ++j)
        s += ain[m][j] * ldf(w_out, j, isbf);
      s += __shfl_down(s, 8);
      s += __shfl_down(s, 4);
      s += __shfl_down(s, 2);
      s += __shfl_down(s, 1);
      int node = nb + p * 32 + m;
      if (c == 0) {
        float logit = s + ldf(b_out, 0, isbf);
        float o = 1.f / (1.f + __expf(-logit));
        if (isbf) ((u16*)out)[node] = f2bf(o);
        else ((float*)out)[node] = o;
      }
    }
  }
}

extern "C" void kernel_launch(void* const* d_in, const int* in_sizes, int n_in,
                              void* d_out, int out_size, void* d_ws, size_t ws_size,
                              hipStream_t stream) {
  const void* x      = d_in[0];
  const int* ei      = (const int*)d_in[1];
  const void* w_rel  = d_in[2];
  const void* b_rel  = d_in[3];
  const void* w_root = d_in[4];
  const void* w_in   = d_in[5];
  const void* b_in   = d_in[6];
  const void* w_hid  = d_in[7];
  const void* b_hid  = d_in[8];
  const void* w_out  = d_in[9];
  const void* b_out  = d_in[10];
  (void)d_ws; (void)ws_size; (void)in_sizes; (void)n_in; (void)out_size;

  sniff_kernel<<<1, 64, 0, stream>>>((const u32*)x);
  prep_kernel<<<(NREP * N_NODES + 255) / 256, 256, 0, stream>>>(x, w_hid);
  gather_kernel<<<N_EDGES / 8 / 256, 256, 0, stream>>>(ei);
  apply_kernel<<<NPART * PBLK, 256, APPLY_LDS, stream>>>(ei);
  reduce_kernel<<<(N_NODES + 255) / 256, 256, 0, stream>>>();
  mlp_kernel<<<N_NODES / MT, 512, LDS_TOTAL, stream>>>(
      w_rel, b_rel, w_root, w_in, b_in, b_hid, w_out, b_out, d_out);
}

// Round 8
// 588.362 us; speedup vs baseline: 1.3756x; 1.0027x over previous
//
#include <hip/hip_runtime.h>

#define N_NODES 200000
#define N_EDGES 6400000
#define HID 200
#define NREP 8                    // x-gather replicas (one per XCD)
#define MT 64                    // nodes per block (3125 * 64 = 200000 exactly)

// Packed B (global, register-streamed): g_wpk[l][kh 2][tile 7][ks7 7][lane 64][j 8]
//   = W^T(n = tile*32 + (lane&31), k = (kh*7+ks7)*16 + (lane>>5)*8 + j), zero-pad.
// Per-wave frag = 1024 CONTIGUOUS bytes -> one global_load_dwordx4 per lane.
#define PK_ELEMS (7 * 14 * 512)   // 50176 elems per layer
#define PK_HALF  (PK_ELEMS / 2)

// Packed A in LDS, DE-ALIGNED strides so epilogue column-writes spread banks:
//   frag(band 2, ks 14) stride 528 elems (1056 B = +8 banks), kh-substride 264
//   elems (528 B = +4 banks). elem(m, k) at FR(m>>5, k>>4) + ((k>>3)&1)*264 +
//   (m&31)*8 + (k&7). Reads stay contiguous-per-lane (conflict-free).
#define FR(band, ks) (((band) * 14 + (ks)) * 528)
#define LDS_BIAS 29568            // actp = 28 frags * 528 * 2B
#define LDS_H0S  34560            // biasl = 6*208 f32 = 4992 B
#define LDS_TOTAL 51968           // >= VALU-fallback's 51840 B; 2 blocks/CU

// Scatter partitioning (NO global atomics): 20 partitions x 10K nodes.
#define NPART 20
#define PNODES 10000
#define PBLK 50                   // edge-chunks
#define CHUNK_E (N_EDGES / PBLK)  // 128000 edges, exact
#define APPLY_LDS (PNODES * 4)    // 40000 B

typedef float f32x4 __attribute__((ext_vector_type(4)));
typedef float f32x16 __attribute__((ext_vector_type(16)));
typedef _Float16 f16x8 __attribute__((ext_vector_type(8)));
typedef unsigned short u16;
typedef unsigned int u32;

__device__ __align__(16) float g_agg[N_NODES];           // reduced aggregation
__device__ __align__(16) float g_xf8[NREP * N_NODES];    // fp32 x, per-XCD replica
__device__ __align__(16) float g_wf[6 * HID * HID];      // fp32 (VALU fallback)
__device__ __align__(16) _Float16 g_wpk[6 * PK_ELEMS];   // packed W^T frags
__device__ __align__(16) float g_ev[N_EDGES];            // gathered x[src]
__device__ __align__(16) float g_part[NPART * PBLK * PNODES];  // 40 MB slices
__device__ int g_isbf;

__device__ __forceinline__ float bf2f(u16 u) {
  union { u32 i; float f; } v; v.i = ((u32)u) << 16; return v.f;
}
__device__ __forceinline__ u16 f2bf(float f) {  // RNE
  u32 i = __float_as_uint(f);
  return (u16)((i + 0x7FFFu + ((i >> 16) & 1u)) >> 16);
}
__device__ __forceinline__ float ldf(const void* p, int i, int isbf) {
  return isbf ? bf2f(((const u16*)p)[i]) : ((const float*)p)[i];
}

// ---- rank-2 MFMA layout self-test for 32x32x16_f16, compile-time ref ----
constexpr int sf1(int m) { return (m & 7) + 1; }
constexpr int sf2(int m) { return ((m >> 3) & 3) + 2; }
constexpr int sg1(int k) { return (k & 7) + 1; }
constexpr int sg2(int k) { return ((k >> 3) & 1) + 1; }
constexpr int su1(int k) { return ((k * 3) & 7) + 1; }
constexpr int su2(int k) { return ((k >> 2) & 3) + 2; }
constexpr int sw1(int n) { return ((n * 5) & 7) + 1; }
constexpr int sw2(int n) { return ((n >> 3) & 3) + 1; }
constexpr int calcS32(int i, int j) {
  int s = 0;
  for (int k = 0; k < 16; ++k)
    s += (i ? sg2(k) : sg1(k)) * (j ? su2(k) : su1(k));
  return s;
}
__device__ __forceinline__ float refD32(int m, int n) {
  constexpr int S11 = calcS32(0, 0), S12 = calcS32(0, 1), S21 = calcS32(1, 0), S22 = calcS32(1, 1);
  return (float)(sf1(m) * sw1(n) * S11 + sf1(m) * sw2(n) * S12 +
                 sf2(m) * sw1(n) * S21 + sf2(m) * sw2(n) * S22);
}
__device__ int mfma_selftest32(int lane) {
  const int m = lane & 31, kh = lane >> 5;
  f16x8 av, bv;
#pragma unroll
  for (int j = 0; j < 8; ++j) {
    int k = kh * 8 + j;
    av[j] = (_Float16)(float)(sf1(m) * sg1(k) + sf2(m) * sg2(k));
    bv[j] = (_Float16)(float)(su1(k) * sw1(m) + su2(k) * sw2(m));
  }
  f32x16 z;
#pragma unroll
  for (int i = 0; i < 16; ++i) z[i] = 0.f;
  f32x16 d = __builtin_amdgcn_mfma_f32_32x32x16_f16(av, bv, z, 0, 0, 0);
  bool ok0 = true, ok1 = true;
#pragma unroll
  for (int reg = 0; reg < 16; ++reg) {
    int rr = (reg & 3) + 8 * (reg >> 2) + 4 * kh;
    ok0 = ok0 && (d[reg] == refD32(rr, m));
    ok1 = ok1 && (d[reg] == refD32(m, rr));
  }
  return __all(ok0) ? 0 : (__all(ok1) ? 1 : 2);
}

// ---- K0: dtype sniff ----
__global__ void sniff_kernel(const u32* __restrict__ xw) {
  int i = threadIdx.x;  // 64 threads
  u32 e = (xw[i] >> 7) & 0xFFu;
  unsigned long long b = __ballot(e >= 110u && e <= 135u);
  if (i == 0) g_isbf = (__popcll(b) >= 48) ? 1 : 0;
}

// ---- K1: replicate x + packed weights + fallback weights ----
__global__ void prep_kernel(const void* __restrict__ x, const void* __restrict__ w_hid) {
  int t = blockIdx.x * blockDim.x + threadIdx.x;   // 1.6M threads
  int isbf = g_isbf;
  if (t < NREP * N_NODES) {
    int qd = t / N_NODES;
    int node = t - qd * N_NODES;
    g_xf8[t] = ldf(x, node, isbf);
  }
  if (t < 6 * HID * HID) g_wf[t] = ldf(w_hid, t, isbf);
  if (t < 6 * PK_ELEMS) {
    int l = t / PK_ELEMS;
    int r = t - l * PK_ELEMS;
    int h = r / PK_HALF;
    int r2 = r - h * PK_HALF;
    int tile = r2 / 3584;            // 7*512 elems per tile within half
    int r3 = r2 - tile * 3584;
    int ks7 = r3 >> 9;
    int r4 = r3 & 511;
    int ln = r4 >> 3;
    int j = r4 & 7;
    int n = tile * 32 + (ln & 31);
    int k = (h * 7 + ks7) * 16 + (ln >> 5) * 8 + j;
    float v = (n < HID && k < HID) ? ldf(w_hid, (l * HID + k) * HID + n, isbf) : 0.f;
    g_wpk[t] = (_Float16)v;
  }
}

// ---- K2a: gather x[src] -> linear g_ev (XCD-local L2 replica) ----
__global__ void gather_kernel(const int* __restrict__ ei) {
  int t = blockIdx.x * blockDim.x + threadIdx.x;   // 800K threads
  int e = t * 8;
  int xcc;
  asm volatile("s_getreg_b32 %0, hwreg(HW_REG_XCC_ID)" : "=s"(xcc));
  const float* xf = g_xf8 + (size_t)(xcc & (NREP - 1)) * N_NODES;
  bool is64 = ((ei[1] | ei[3] | ei[5] | ei[7]) == 0);
  int s[8];
  if (is64) {
#pragma unroll
    for (int i = 0; i < 4; ++i) {
      int4 a = *(const int4*)(ei + 2 * e + 4 * i);
      s[2 * i] = a.x; s[2 * i + 1] = a.z;
    }
  } else {
#pragma unroll
    for (int i = 0; i < 2; ++i) {
      int4 a = *(const int4*)(ei + e + 4 * i);
      s[4 * i] = a.x; s[4 * i + 1] = a.y; s[4 * i + 2] = a.z; s[4 * i + 3] = a.w;
    }
  }
  float v[8];
#pragma unroll
  for (int i = 0; i < 8; ++i) v[i] = xf[s[i]];
  *(float4*)(g_ev + e) = (float4){v[0], v[1], v[2], v[3]};
  *(float4*)(g_ev + e + 4) = (float4){v[4], v[5], v[6], v[7]};
}

// ---- K2b: partitioned scatter via LDS atomics; ZERO global atomics ----
__global__ __launch_bounds__(256) void apply_kernel(const int* __restrict__ ei) {
  extern __shared__ float part[];   // PNODES floats = 40 KB
  const int tid = threadIdx.x;
  const int p = blockIdx.x / PBLK;
  const int cb = blockIdx.x - p * PBLK;
  const int lo = p * PNODES;
  float4* pv = (float4*)part;
  for (int c = tid; c < PNODES / 4; c += 256) pv[c] = (float4){0.f, 0.f, 0.f, 0.f};
  __syncthreads();
  const bool is64 = ((ei[1] | ei[3] | ei[5] | ei[7]) == 0);
  const int base = cb * CHUNK_E;
  for (int g = 0; g < CHUNK_E / (256 * 4); ++g) {   // 125 iterations
    int idx = base + (g * 256 + tid) * 4;
    float4 v = *(const float4*)(g_ev + idx);
    int d0, d1, d2, d3;
    if (is64) {
      int4 b0 = *(const int4*)(ei + 2 * (size_t)N_EDGES + 2 * (size_t)idx);
      int4 b1 = *(const int4*)(ei + 2 * (size_t)N_EDGES + 2 * (size_t)idx + 4);
      d0 = b0.x; d1 = b0.z; d2 = b1.x; d3 = b1.z;
    } else {
      int4 b = *(const int4*)(ei + N_EDGES + idx);
      d0 = b.x; d1 = b.y; d2 = b.z; d3 = b.w;
    }
    unsigned u0 = (unsigned)(d0 - lo), u1 = (unsigned)(d1 - lo);
    unsigned u2 = (unsigned)(d2 - lo), u3 = (unsigned)(d3 - lo);
    if (u0 < PNODES) __hip_atomic_fetch_add(&part[u0], v.x, __ATOMIC_RELAXED, __HIP_MEMORY_SCOPE_WORKGROUP);
    if (u1 < PNODES) __hip_atomic_fetch_add(&part[u1], v.y, __ATOMIC_RELAXED, __HIP_MEMORY_SCOPE_WORKGROUP);
    if (u2 < PNODES) __hip_atomic_fetch_add(&part[u2], v.z, __ATOMIC_RELAXED, __HIP_MEMORY_SCOPE_WORKGROUP);
    if (u3 < PNODES) __hip_atomic_fetch_add(&part[u3], v.w, __ATOMIC_RELAXED, __HIP_MEMORY_SCOPE_WORKGROUP);
  }
  __syncthreads();
  float* gp = g_part + (size_t)blockIdx.x * PNODES;
  for (int c = tid; c < PNODES / 4; c += 256)
    *(float4*)(gp + c * 4) = pv[c];
}

// ---- K2c: reduce slices -> g_agg (coalesced; no atomics) ----
__global__ void reduce_kernel() {
  int n = blockIdx.x * 256 + threadIdx.x;
  if (n >= N_NODES) return;
  int p = n / PNODES;
  int off = n - p * PNODES;
  const float* base = g_part + (size_t)p * PBLK * PNODES + off;
  float s = 0.f;
#pragma unroll
  for (int c = 0; c < PBLK; ++c) s += base[(size_t)c * PNODES];
  g_agg[n] = s;
}

// ---- K3: fused MLP, 32x32x16 MFMA. B streams GLOBAL->REGISTER (1KB
// coalesced frags from g_wpk, L2-resident, compiler-pipelined vmcnt):
// NO weight staging, NO vmcnt(0) drains, 2 barriers/layer (was 5).
// A in LDS with de-aligned strides (528/264) -> epilogue writes ~2-way
// banks instead of 8-way. Bias LDS-resident. acc 32 + af 28 + B-in-flight
// regs; __launch_bounds__(512,4) caps VGPR at 128 -> 2 blocks/CU. ----
__global__ __launch_bounds__(512, 4) void mlp_kernel(
    const void* __restrict__ w_rel, const void* __restrict__ b_rel, const void* __restrict__ w_root,
    const void* __restrict__ w_in, const void* __restrict__ b_in,
    const void* __restrict__ b_hid, const void* __restrict__ w_out, const void* __restrict__ b_out,
    void* __restrict__ out) {
  extern __shared__ char smem[];
  _Float16* actp = (_Float16*)smem;
  float* biasl = (float*)(smem + LDS_BIAS);
  float* h0s = (float*)(smem + LDS_H0S);

  const int tid = threadIdx.x;
  const int nb = blockIdx.x * MT;
  const int isbf = g_isbf;
  const int lane = tid & 63;
  const int wv = tid >> 6;          // 8 waves
  const int band = wv >> 2;         // 2 bands x 32 rows
  const int cg = wv & 3;            // 4 col groups
  const int t0 = cg * 2;            // first n-tile (cg3 owns only tile 6)
  const int m32 = lane & 31;
  const int khl = lane >> 5;

  const int mode = mfma_selftest32(lane);

  // GraphConv h0 + bias preload (once per block)
  if (tid < MT) {
    int node = nb + tid;
    h0s[tid] = g_agg[node] * ldf(w_rel, 0, isbf) + ldf(b_rel, 0, isbf) +
               g_xf8[node] * ldf(w_root, 0, isbf);
  }
  for (int i = tid; i < 6 * 208; i += 512) {
    int l = i / 208, c = i - l * 208;
    biasl[i] = (c < HID) ? ldf(b_hid, l * HID + c, isbf) : 0.f;
  }
  __syncthreads();

  if (mode < 2) {
    // Input layer -> packed A; cols >= HID zeroed.
    for (int u = tid; u < MT * 28; u += 512) {
      int m = u / 28, g = u - m * 28;
      int ks = g >> 1, kh = g & 1;
      float h0v = h0s[m];
      f16x8 pv;
#pragma unroll
      for (int j = 0; j < 8; ++j) {
        int col = ks * 16 + kh * 8 + j;
        float v = 0.f;
        if (col < HID) v = fmaxf(h0v * ldf(w_in, col, isbf) + ldf(b_in, col, isbf), 0.f);
        pv[j] = (_Float16)v;
      }
      *(f16x8*)(actp + FR(m >> 5, ks) + kh * 264 + (m & 31) * 8) = pv;
    }
    __syncthreads();

    for (int l = 0; l < 6; ++l) {
      f32x16 acc0, acc1;
#pragma unroll
      for (int i = 0; i < 16; ++i) { acc0[i] = 0.f; acc1[i] = 0.f; }

#pragma unroll
      for (int h = 0; h < 2; ++h) {
        const _Float16* gb = g_wpk + (size_t)l * PK_ELEMS + h * PK_HALF + lane * 8;
        f16x8 af[7];
#pragma unroll
        for (int i = 0; i < 7; ++i)
          af[i] = *(const f16x8*)(actp + FR(band, h * 7 + i) + khl * 264 + m32 * 8);
        if (cg < 3) {
#pragma unroll
          for (int i = 0; i < 7; ++i) {
            f16x8 b0 = *(const f16x8*)(gb + (t0 * 7 + i) * 512);
            f16x8 b1 = *(const f16x8*)(gb + ((t0 + 1) * 7 + i) * 512);
            acc0 = __builtin_amdgcn_mfma_f32_32x32x16_f16(af[i], b0, acc0, 0, 0, 0);
            acc1 = __builtin_amdgcn_mfma_f32_32x32x16_f16(af[i], b1, acc1, 0, 0, 0);
          }
        } else {
#pragma unroll
          for (int i = 0; i < 7; ++i) {
            f16x8 b0 = *(const f16x8*)(gb + (6 * 7 + i) * 512);
            acc0 = __builtin_amdgcn_mfma_f32_32x32x16_f16(af[i], b0, acc0, 0, 0, 0);
          }
        }
      }
      __syncthreads();  // all waves' A reads done before in-place writes

      // epilogue: bias + relu -> packed A (de-aligned strides: ~2-way banks)
      if (mode == 0) {
        {
          int col = t0 * 32 + m32;
          float bias = biasl[l * 208 + col];
          _Float16* dst = actp + FR(band, col >> 4) + ((col >> 3) & 1) * 264 + (col & 7);
#pragma unroll
          for (int reg = 0; reg < 16; ++reg) {
            int rr = (reg & 3) + 8 * (reg >> 2) + 4 * khl;
            dst[rr * 8] = (_Float16)fmaxf(acc0[reg] + bias, 0.f);
          }
        }
        if (cg < 3) {
          int col = (t0 + 1) * 32 + m32;
          float bias = biasl[l * 208 + col];
          _Float16* dst = actp + FR(band, col >> 4) + ((col >> 3) & 1) * 264 + (col & 7);
#pragma unroll
          for (int reg = 0; reg < 16; ++reg) {
            int rr = (reg & 3) + 8 * (reg >> 2) + 4 * khl;
            dst[rr * 8] = (_Float16)fmaxf(acc1[reg] + bias, 0.f);
          }
        }
      } else {  // mode 1: transposed D
#pragma unroll
        for (int reg = 0; reg < 16; ++reg) {
          int cc = (reg & 3) + 8 * (reg >> 2) + 4 * khl;
          {
            int col = t0 * 32 + cc;
            float v = acc0[reg] + biasl[l * 208 + col];
            actp[FR(band, col >> 4) + ((col >> 3) & 1) * 264 + m32 * 8 + (col & 7)] =
                (_Float16)fmaxf(v, 0.f);
          }
          if (cg < 3) {
            int col = (t0 + 1) * 32 + cc;
            float v = acc1[reg] + biasl[l * 208 + col];
            actp[FR(band, col >> 4) + ((col >> 3) & 1) * 264 + m32 * 8 + (col & 7)] =
                (_Float16)fmaxf(v, 0.f);
          }
        }
      }
      __syncthreads();  // writes visible before next layer's A reads
    }

    // Output layer: 8 threads/row x 25 cols, packed-A addressing
    {
      int m = tid >> 3, c = tid & 7;
      float s = 0.f;
#pragma unroll
      for (int j = c * 25; j < c * 25 + 25; ++j) {
        _Float16 a = actp[FR(m >> 5, j >> 4) + ((j >> 3) & 1) * 264 + (m & 31) * 8 + (j & 7)];
        s += (float)a * ldf(w_out, j, isbf);
      }
      s += __shfl_down(s, 4);
      s += __shfl_down(s, 2);
      s += __shfl_down(s, 1);
      if (c == 0) {
        float logit = s + ldf(b_out, 0, isbf);
        float o = 1.f / (1.f + __expf(-logit));
        if (isbf) ((u16*)out)[nb + m] = f2bf(o);
        else ((float*)out)[nb + m] = o;
      }
    }
  } else {
    // ---- VALU fallback (defensive; 2 passes of 32 rows) ----
    float(*fA)[201] = (float(*)[201])smem;                    // 32x201 fp32
    float(*fB)[201] = (float(*)[201])(smem + 32 * 201 * 4);
    float* h0f = (float*)(smem + 64 * 201 * 4);
    for (int p = 0; p < 2; ++p) {
      __syncthreads();
      if (tid < 32) {
        int node = nb + p * 32 + tid;
        h0f[tid] = g_agg[node] * ldf(w_rel, 0, isbf) + ldf(b_rel, 0, isbf) +
                   g_xf8[node] * ldf(w_root, 0, isbf);
      }
      __syncthreads();
      for (int i = tid; i < 32 * HID; i += 512) {
        int mm = i / HID, ff = i - mm * HID;
        float v = h0f[mm] * ldf(w_in, ff, isbf) + ldf(b_in, ff, isbf);
        fA[mm][ff] = v > 0.f ? v : 0.f;
      }
      __syncthreads();
      const int m = tid >> 4, c = tid & 15;
      float(*ain)[201] = fA;
      float(*aout)[201] = fB;
      for (int l = 0; l < 6; ++l) {
        float acc[13];
#pragma unroll
        for (int jj = 0; jj < 13; ++jj) {
          int j = c * 13 + jj;
          acc[jj] = (j < HID) ? ldf(b_hid, l * HID + j, isbf) : 0.f;
        }
        const float* wl = g_wf + l * HID * HID;
        for (int k = 0; k < HID; ++k) {
          float a = ain[m][k];
          const float* wr = wl + k * HID;
#pragma unroll
          for (int jj = 0; jj < 13; ++jj) {
            int j = c * 13 + jj;
            if (j < HID) acc[jj] = fmaf(a, wr[j], acc[jj]);
          }
        }
        __syncthreads();
#pragma unroll
        for (int jj = 0; jj < 13; ++jj) {
          int j = c * 13 + jj;
          if (j < HID) aout[m][j] = fmaxf(acc[jj], 0.f);
        }
        float(*tsw)[201] = ain; ain = aout; aout = tsw;
        __syncthreads();
      }
      float s = 0.f;
      for (int j = c * 13; j < c * 13 + 13 && j < HID; ++j)
        s += ain[m][j] * ldf(w_out, j, isbf);
      s += __shfl_down(s, 8);
      s += __shfl_down(s, 4);
      s += __shfl_down(s, 2);
      s += __shfl_down(s, 1);
      int node = nb + p * 32 + m;
      if (c == 0) {
        float logit = s + ldf(b_out, 0, isbf);
        float o = 1.f / (1.f + __expf(-logit));
        if (isbf) ((u16*)out)[node] = f2bf(o);
        else ((float*)out)[node] = o;
      }
    }
  }
}

extern "C" void kernel_launch(void* const* d_in, const int* in_sizes, int n_in,
                              void* d_out, int out_size, void* d_ws, size_t ws_size,
                              hipStream_t stream) {
  const void* x      = d_in[0];
  const int* ei      = (const int*)d_in[1];
  const void* w_rel  = d_in[2];
  const void* b_rel  = d_in[3];
  const void* w_root = d_in[4];
  const void* w_in   = d_in[5];
  const void* b_in   = d_in[6];
  const void* w_hid  = d_in[7];
  const void* b_hid  = d_in[8];
  const void* w_out  = d_in[9];
  const void* b_out  = d_in[10];
  (void)d_ws; (void)ws_size; (void)in_sizes; (void)n_in; (void)out_size;

  sniff_kernel<<<1, 64, 0, stream>>>((const u32*)x);
  prep_kernel<<<(NREP * N_NODES + 255) / 256, 256, 0, stream>>>(x, w_hid);
  gather_kernel<<<N_EDGES / 8 / 256, 256, 0, stream>>>(ei);
  apply_kernel<<<NPART * PBLK, 256, APPLY_LDS, stream>>>(ei);
  reduce_kernel<<<(N_NODES + 255) / 256, 256, 0, stream>>>();
  mlp_kernel<<<N_NODES / MT, 512, LDS_TOTAL, stream>>>(
      w_rel, b_rel, w_root, w_in, b_in, b_hid, w_out, b_out, d_out);
}